// Round 9
// baseline (1085.613 us; speedup 1.0000x reference)
//
#include <hip/hip_runtime.h>

// RetinaNet head, bf16 implicit-GEMM conv3x3 via MFMA 16x16x32.
// Round 9: deep-pipeline core at 3 blocks/CU.
//  - A-LDS shrunk to 272 pos (17.4KB): 2D 2-row x 64-col tiles for levels 0-1,
//    flat-128 for levels 2-4 (<=243 pos). Unified read path (Wp=68 vs W+2).
//  - B 4-deep (32KB), issue 3 taps ahead (~390cy latency budget), counted
//    vmcnt (steady 4; taps7/8: 9; tail 2/0) + raw barriers. Total LDS 50176.
//  - A restage: reg-prefetch (5 loads/wave, uniform) at tap6, ds_write at
//    tap8-end behind a barrier; lgkmcnt(0) at tap0 entry.
//  - 133 tiles/n (100 lvl0 + 25 lvl1 + 5/2/1 flat). Dual-branch towers
//    (br = bid&1 interleave), cls-out nt-fastest, separate reg-out.
// Packed B layout per tensor: [nt][cc 8][tap 9][co 128][piece 4][8 bf16],
// piece pre-XOR-swizzled by ((co>>1)&3). A pieces pre-swizzled by ((pos>>1)&3).

typedef __bf16 v8bf __attribute__((ext_vector_type(8)));
typedef float f32x4 __attribute__((ext_vector_type(4)));
typedef unsigned int u32x4 __attribute__((ext_vector_type(4)));

__device__ __forceinline__ v8bf zero8() {
  v8bf v;
#pragma unroll
  for (int j = 0; j < 8; ++j) v[j] = (__bf16)0.0f;
  return v;
}

__device__ __forceinline__ void glds16(const void* g, void* l) {
  __builtin_amdgcn_global_load_lds((const __attribute__((address_space(1))) unsigned int*)g,
                                   (__attribute__((address_space(3))) unsigned int*)l, 16, 0, 0);
}

// ---------------- prep: NCHW fp32 -> NHWC bf16 ----------------
__global__ __launch_bounds__(256)
void prep_in(const float* __restrict__ f0, const float* __restrict__ f1,
             const float* __restrict__ f2, const float* __restrict__ f3,
             const float* __restrict__ f4, __bf16* __restrict__ dst)
{
  int oct = blockIdx.x * 256 + threadIdx.x;
  if (oct >= 1707904) return;             // 13663232/8
  int el = oct << 3;
  int c0 = el & 255;
  int pix = el >> 8;
  const float* s; int HW, hw, n;
  if (pix < 40000)      { s = f0; HW = 10000; int p = pix;         n = p / 10000; hw = p - n * 10000; }
  else if (pix < 50000) { s = f1; HW = 2500;  int p = pix - 40000; n = p / 2500;  hw = p - n * 2500;  }
  else if (pix < 52500) { s = f2; HW = 625;   int p = pix - 50000; n = p / 625;   hw = p - n * 625;   }
  else if (pix < 53176) { s = f3; HW = 169;   int p = pix - 52500; n = p / 169;   hw = p - n * 169;   }
  else                  { s = f4; HW = 49;    int p = pix - 53176; n = p / 49;    hw = p - n * 49;    }
  const float* sp = s + (n * 256 + c0) * HW + hw;
  v8bf v;
#pragma unroll
  for (int j = 0; j < 8; ++j) v[j] = (__bf16)sp[j * HW];
  *(v8bf*)(dst + el) = v;
}

// ------ prep: all 10 weight tensors, OIHW fp32 -> packed B bf16 ------
__global__ __launch_bounds__(256)
void prep_w_all(const float* __restrict__ cls_w, const float* __restrict__ reg_w,
                const float* __restrict__ cls_ow, const float* __restrict__ reg_ow,
                __bf16* __restrict__ wb)
{
  int t = blockIdx.x * 256 + threadIdx.x;
  const float* src; __bf16* dst; int CO, within;
  if (t < 589824) {                        // 8 tower tensors x 73728 octets
    int tensor = t / 73728; within = t % 73728;
    src = tensor < 4 ? cls_w + tensor * 589824 : reg_w + (tensor - 4) * 589824;
    dst = wb + (size_t)tensor * 589824; CO = 256;
  } else if (t < 811008) {                 // cls-out: 6*8*9*128*4
    within = t - 589824; src = cls_ow; dst = wb + 8 * 589824; CO = 720;
  } else {                                 // reg-out: 1*8*9*128*4
    within = t - 811008; src = reg_ow; dst = wb + 8 * 589824 + 1769472; CO = 36;
  }
  int p = within & 3; int xx = within >> 2;
  int co = xx & 127; xx >>= 7;
  int tap = xx % 9; xx /= 9;
  int cc = xx & 7; int nt = xx >> 3;
  int l = p ^ ((co >> 1) & 3);            // logical piece held at physical p
  int cog = nt * 128 + co;
  v8bf v = zero8();
  if (cog < CO) {
    const float* sp = src + ((size_t)cog * 256 + cc * 32 + l * 8) * 9 + tap;
#pragma unroll
    for (int j = 0; j < 8; ++j) v[j] = (__bf16)sp[j * 9];
  }
  *(v8bf*)(dst + ((size_t)(((nt * 8 + cc) * 9 + tap) * 128 + co) * 32 + p * 8)) = v;
}

// ---------------- geometry: 133 tiles per n ----------------
struct Geo { int is2d, W, H, HW, pbase, obC, obR, g1, g2; };
__device__ __forceinline__ Geo decode133(int r) {
  Geo g;
  if (r < 100)      { g.is2d=1; g.W=100;g.H=100;g.HW=10000;g.pbase=0;     g.obC=0;       g.obR=0;      g.g1=(r>>1)*2;    g.g2=(r&1)*64; }
  else if (r < 125) { g.is2d=1; g.W=50; g.H=50; g.HW=2500; g.pbase=40000; g.obC=7200000; g.obR=360000; g.g1=(r-100)*2;   g.g2=0; }
  else if (r < 130) { g.is2d=0; g.W=25; g.H=25; g.HW=625;  g.pbase=50000; g.obC=9000000; g.obR=450000; g.g1=(r-125)*128; g.g2=0; }
  else if (r < 132) { g.is2d=0; g.W=13; g.H=13; g.HW=169;  g.pbase=52500; g.obC=9450000; g.obR=472500; g.g1=(r-130)*128; g.g2=0; }
  else              { g.is2d=0; g.W=7;  g.H=7;  g.HW=49;   g.pbase=53176; g.obC=9571680; g.obR=478584; g.g1=0;           g.g2=0; }
  return g;
}

// -------- conv core: 128px x 128co tile, 4-deep B, counted vmcnt --------
__device__ __forceinline__ void conv_core(const char* __restrict__ ws, unsigned soA,
    unsigned zp, const char* __restrict__ wnt, int is2d, int W, int H,
    int g1, int g2, f32x4 (&acc)[4][4])
{
  __shared__ __align__(16) char ldsA[17408];   // 272 pos * 64B
  __shared__ __align__(16) char ldsB[32768];   // 4 bufs * 8KB (one tap each)
  const int tid = threadIdx.x, lane = tid & 63, wv = tid >> 6;
  const int wm = wv >> 1, wn = wv & 1, la = lane & 15, kg = lane >> 4;
  const int Wp = is2d ? 68 : (W + 2);
  const int rowlo = is2d ? (g1 - 1) : (g1 / W - 1);
  const int c0 = g2, p0 = g1;

  // ---- A source ws-offsets (5 loads/thread; +64B per cc) + LDS write addrs ----
  unsigned u[5];
  int dwr[5];
#pragma unroll
  for (int j = 0; j < 5; ++j) {
    int pos, pp;
    if (j < 4) { pos = tid; pp = j; }
    else { pos = 256 + (lane >> 2); pp = lane & 3; }
    int hr = pos / Wp, hc = pos - hr * Wp;
    int ar = rowlo + hr;
    int ac = is2d ? (c0 - 1 + hc) : (hc - 1);
    int swz = (pos >> 1) & 3;
    bool ok = (ar >= 0) & (ar < H) & (ac >= 0) & (ac < W);
    u[j] = ok ? (soA + (unsigned)(ar * W + ac) * 512u + (unsigned)((pp ^ swz) << 4))
              : (zp + (unsigned)(pp << 4));
    dwr[j] = pos * 64 + pp * 16;
  }

  // frag center positions (tap dh=dw=0)
  int pos0[4];
#pragma unroll
  for (int f = 0; f < 4; ++f) {
    if (is2d) pos0[f] = (wm + 1) * 68 + (f * 16 + la + 1);
    else {
      int p = p0 + (wm * 4 + f) * 16 + la;
      int h = p / W;
      pos0[f] = (h - rowlo) * Wp + (p - h * W + 1);
    }
  }
  int boff[4];
#pragma unroll
  for (int nj = 0; nj < 4; ++nj) {
    int co = wn * 64 + nj * 16 + la;
    boff[nj] = (co << 6) + ((kg << 4) ^ (((co >> 1) & 3) << 4));
  }
  const char* bq = wnt + wv * 2048 + lane * 16;  // per-wave B src base
  char* bd = (char*)ldsB + wv * 2048;            // per-wave B dst base

  u32x4 areg[5];

  // ---- prologue: A(cc0) regs -> lds ; issue B(0),B(1),B(2) ----
#pragma unroll
  for (int j = 0; j < 5; ++j) { areg[j] = *(const u32x4*)(ws + u[j]); u[j] += 64u; }
  asm volatile("s_waitcnt vmcnt(0)" ::: "memory");
#pragma unroll
  for (int j = 0; j < 5; ++j) *(u32x4*)(ldsA + dwr[j]) = areg[j];
#pragma unroll
  for (int q0 = 0; q0 < 3; ++q0) {
    const char* s_ = bq + q0 * 8192; char* d_ = bd + q0 * 8192;
    glds16(s_, d_); glds16(s_ + 1024, d_ + 1024);
  }

  int pb = 0;                              // = q % 4
  for (int cc = 0; cc < 8; ++cc) {
    const bool lastc = (cc == 7);
#pragma unroll
    for (int tap = 0; tap < 9; ++tap) {
      // ---- entry wait (per-wave FIFO-accounted) ----
      if (tap == 0) {
        asm volatile("s_waitcnt lgkmcnt(0)" ::: "memory");  // A ds_writes visible pre-barrier
        asm volatile("s_waitcnt vmcnt(4)" ::: "memory");
      } else if (tap <= 6) {
        asm volatile("s_waitcnt vmcnt(4)" ::: "memory");
      } else if (tap == 7) {
        if (lastc) { asm volatile("s_waitcnt vmcnt(2)" ::: "memory"); }
        else       { asm volatile("s_waitcnt vmcnt(9)" ::: "memory"); }
      } else {
        if (lastc) { asm volatile("s_waitcnt vmcnt(0)" ::: "memory"); }
        else       { asm volatile("s_waitcnt vmcnt(9)" ::: "memory"); }
      }
      __builtin_amdgcn_s_barrier();
      // ---- issue B(q+3) into buf (q+3)%4 ----
      int q = cc * 9 + tap;
      if (q + 3 <= 71) {
        const char* s_ = bq + (size_t)(q + 3) * 8192;
        char* d_ = bd + ((q + 3) & 3) * 8192;
        glds16(s_, d_); glds16(s_ + 1024, d_ + 1024);
      }
      // ---- A(cc+1) register prefetch at tap 6 ----
      if (tap == 6 && !lastc) {
#pragma unroll
        for (int j = 0; j < 5; ++j) { areg[j] = *(const u32x4*)(ws + u[j]); u[j] += 64u; }
      }
      // ---- fragment reads ----
      const char* bbuf = (const char*)ldsB + pb * 8192;
      v8bf bfr[4];
#pragma unroll
      for (int nj = 0; nj < 4; ++nj) bfr[nj] = *(const v8bf*)(bbuf + boff[nj]);
      const int dt = (tap / 3 - 1) * Wp + (tap % 3 - 1);
      v8bf afr[4];
#pragma unroll
      for (int f = 0; f < 4; ++f) {
        int pos = pos0[f] + dt;
        afr[f] = *(const v8bf*)(ldsA + ((pos << 6) + ((kg << 4) ^ (((pos >> 1) & 3) << 4))));
      }
      __builtin_amdgcn_s_setprio(1);
#pragma unroll
      for (int f = 0; f < 4; ++f)
#pragma unroll
        for (int nj = 0; nj < 4; ++nj)
          acc[f][nj] = __builtin_amdgcn_mfma_f32_16x16x32_bf16(afr[f], bfr[nj], acc[f][nj], 0, 0, 0);
      __builtin_amdgcn_s_setprio(0);
      pb = (pb + 1) & 3;
      // ---- A restage at tap 8 (all waves' A reads done -> barrier) ----
      if (tap == 8 && !lastc) {
        __builtin_amdgcn_s_barrier();
        asm volatile("s_waitcnt vmcnt(4)" ::: "memory");    // A regs landed; 2 B-issues stay in flight
#pragma unroll
        for (int j = 0; j < 5; ++j) *(u32x4*)(ldsA + dwr[j]) = areg[j];
      }
    }
  }
}

// ---------------- tower conv (+bias, ReLU, bf16 NHWC out), dual-branch ----------------
__global__ __launch_bounds__(256, 3)
void conv_tower(const char* __restrict__ ws,
                unsigned so0, __bf16* __restrict__ dst0, const __bf16* __restrict__ w0, const float* __restrict__ b0,
                unsigned so1, __bf16* __restrict__ dst1, const __bf16* __restrict__ w1, const float* __restrict__ b1,
                unsigned zp, int dual)
{
  int bid = blockIdx.x;
  int br = 0, m2;
  if (dual) { br = bid & 1; m2 = bid >> 1; } else { m2 = bid; }
  int nt = m2 & 1, mtn = m2 >> 1;          // mtn 0..531
  int n = mtn / 133, r = mtn - n * 133;
  Geo g = decode133(r);
  unsigned soA = (br ? so1 : so0) + (unsigned)(g.pbase + n * g.HW) * 512u;
  const __bf16* wt = (br ? w1 : w0) + nt * 294912;
  const float* bias = br ? b1 : b0;
  __bf16* dst = br ? dst1 : dst0;

  f32x4 acc[4][4];
#pragma unroll
  for (int f = 0; f < 4; ++f)
#pragma unroll
    for (int j = 0; j < 4; ++j)
#pragma unroll
      for (int k = 0; k < 4; ++k) acc[f][j][k] = 0.0f;

  conv_core(ws, soA, zp, (const char*)wt, g.is2d, g.W, g.H, g.g1, g.g2, acc);

  int lane = threadIdx.x & 63, wv = threadIdx.x >> 6;
  int wm = wv >> 1, wn = wv & 1, la = lane & 15, kg = lane >> 4;
  size_t nb = (size_t)(g.pbase + n * g.HW);
#pragma unroll
  for (int f = 0; f < 4; ++f) {
#pragma unroll
    for (int nj = 0; nj < 4; ++nj) {
      int cob = nt * 128 + wn * 64 + nj * 16 + la;
      float bs = bias[cob];
#pragma unroll
      for (int rr = 0; rr < 4; ++rr) {
        int pix; bool ok;
        if (g.is2d) {
          int row = g.g1 + wm, col = g.g2 + f * 16 + kg * 4 + rr;
          ok = (row < g.H) & (col < g.W); pix = row * g.W + col;
        } else {
          pix = g.g1 + (wm * 4 + f) * 16 + kg * 4 + rr;
          ok = pix < g.HW;
        }
        if (ok)
          dst[((nb + pix) << 8) + cob] = (__bf16)fmaxf(acc[f][nj][rr] + bs, 0.0f);
      }
    }
  }
}

// ---------------- cls out conv (fp32 -> d_out), 720 co = 6 nt tiles ----------------
__global__ __launch_bounds__(256, 3)
void conv_cls_out(const char* __restrict__ ws, unsigned soA,
                  float* __restrict__ out, const __bf16* __restrict__ wco,
                  const float* __restrict__ bco, unsigned zp)
{
  int bid = blockIdx.x;
  int nt = bid % 6, mtn = bid / 6;
  int n = mtn / 133, r = mtn - n * 133;
  Geo g = decode133(r);
  unsigned so = soA + (unsigned)(g.pbase + n * g.HW) * 512u;

  f32x4 acc[4][4];
#pragma unroll
  for (int f = 0; f < 4; ++f)
#pragma unroll
    for (int j = 0; j < 4; ++j)
#pragma unroll
      for (int k = 0; k < 4; ++k) acc[f][j][k] = 0.0f;

  conv_core(ws, so, zp, (const char*)(wco + nt * 294912), g.is2d, g.W, g.H, g.g1, g.g2, acc);

  int lane = threadIdx.x & 63, wv = threadIdx.x >> 6;
  int wm = wv >> 1, wn = wv & 1, la = lane & 15, kg = lane >> 4;
#pragma unroll
  for (int f = 0; f < 4; ++f) {
#pragma unroll
    for (int nj = 0; nj < 4; ++nj) {
      int cob = nt * 128 + wn * 64 + nj * 16 + la;
      if (cob < 720) {
        float bs = bco[cob];
#pragma unroll
        for (int rr = 0; rr < 4; ++rr) {
          int pix; bool ok;
          if (g.is2d) {
            int row = g.g1 + wm, col = g.g2 + f * 16 + kg * 4 + rr;
            ok = (row < g.H) & (col < g.W); pix = row * g.W + col;
          } else {
            pix = g.g1 + (wm * 4 + f) * 16 + kg * 4 + rr;
            ok = pix < g.HW;
          }
          if (ok)
            out[(size_t)n * 9606960 + g.obC + (size_t)pix * 720 + cob] = acc[f][nj][rr] + bs;
        }
      }
    }
  }
}

// ---------------- reg out conv (fp32 -> d_out), 36 co ----------------
__global__ __launch_bounds__(256, 3)
void conv_reg_out(const char* __restrict__ ws, unsigned soA,
                  float* __restrict__ out, const __bf16* __restrict__ wro,
                  const float* __restrict__ bro, unsigned zp)
{
  int mtn = blockIdx.x;
  int n = mtn / 133, r = mtn - n * 133;
  Geo g = decode133(r);
  unsigned so = soA + (unsigned)(g.pbase + n * g.HW) * 512u;

  f32x4 acc[4][4];
#pragma unroll
  for (int f = 0; f < 4; ++f)
#pragma unroll
    for (int j = 0; j < 4; ++j)
#pragma unroll
      for (int k = 0; k < 4; ++k) acc[f][j][k] = 0.0f;

  conv_core(ws, so, zp, (const char*)wro, g.is2d, g.W, g.H, g.g1, g.g2, acc);

  int lane = threadIdx.x & 63, wv = threadIdx.x >> 6;
  int wm = wv >> 1, wn = wv & 1, la = lane & 15, kg = lane >> 4;
#pragma unroll
  for (int f = 0; f < 4; ++f) {
#pragma unroll
    for (int nj = 0; nj < 4; ++nj) {
      int cob = wn * 64 + nj * 16 + la;
      if (cob < 36) {
        float bs = bro[cob];
#pragma unroll
        for (int rr = 0; rr < 4; ++rr) {
          int pix; bool ok;
          if (g.is2d) {
            int row = g.g1 + wm, col = g.g2 + f * 16 + kg * 4 + rr;
            ok = (row < g.H) & (col < g.W); pix = row * g.W + col;
          } else {
            pix = g.g1 + (wm * 4 + f) * 16 + kg * 4 + rr;
            ok = pix < g.HW;
          }
          if (ok)
            out[38427840 + (size_t)n * 480348 + g.obR + (size_t)pix * 36 + cob] = acc[f][nj][rr] + bs;
        }
      }
    }
  }
}

extern "C" void kernel_launch(void* const* d_in, const int* in_sizes, int n_in,
                              void* d_out, int out_size, void* d_ws, size_t ws_size,
                              hipStream_t stream) {
  (void)in_sizes; (void)n_in; (void)out_size;
  const float* feat0 = (const float*)d_in[0];
  const float* feat1 = (const float*)d_in[1];
  const float* feat2 = (const float*)d_in[2];
  const float* feat3 = (const float*)d_in[3];
  const float* feat4 = (const float*)d_in[4];
  const float* cls_w  = (const float*)d_in[5];
  const float* cls_b  = (const float*)d_in[6];
  const float* cls_ow = (const float*)d_in[7];
  const float* cls_ob = (const float*)d_in[8];
  const float* reg_w  = (const float*)d_in[9];
  const float* reg_b  = (const float*)d_in[10];
  const float* reg_ow = (const float*)d_in[11];
  const float* reg_ob = (const float*)d_in[12];
  float* out = (float*)d_out;

  const size_t ACT = 13663232;             // bf16 elems per activation tensor
  const size_t WSEG = 6782976;             // packed weights total elems
  const char* ws = (const char*)d_ws;
  __bf16* base = (__bf16*)d_ws;

  bool fused = ws_size >= (5 * ACT + WSEG + 4096) * 2;
  int nact = fused ? 5 : 3;
  __bf16* A = base + ACT;
  __bf16* B = base + 2 * ACT;
  __bf16* C = fused ? base + 3 * ACT : A;
  __bf16* D = fused ? base + 4 * ACT : B;
  __bf16* wb = base + nact * ACT;

  __bf16* w_cls[4], *w_reg[4];
  for (int li = 0; li < 4; ++li) { w_cls[li] = wb + (size_t)li * 589824; w_reg[li] = wb + (size_t)(4 + li) * 589824; }
  __bf16* wco = wb + 8 * 589824;
  __bf16* wro = wco + 1769472;
  __bf16* zpp = wro + 294912;

  unsigned off_in = 0;
  unsigned off_A = (unsigned)(ACT * 2);
  unsigned off_B = (unsigned)(ACT * 4);
  unsigned off_C = fused ? (unsigned)(ACT * 6) : off_A;
  unsigned off_D = fused ? (unsigned)(ACT * 8) : off_B;
  unsigned off_zp = (unsigned)((nact * ACT + WSEG) * 2);

  hipMemsetAsync(zpp, 0, 8192, stream);
  prep_in<<<6672, 256, 0, stream>>>(feat0, feat1, feat2, feat3, feat4, base);
  prep_w_all<<<3312, 256, 0, stream>>>(cls_w, reg_w, cls_ow, reg_ow, wb);

  const int GT2 = 133 * 4 * 2 * 2;         // 2128 dual
  const int GT1 = 133 * 4 * 2;             // 1064 single
  const int GC  = 133 * 4 * 6;             // 3192
  const int GR  = 133 * 4;                 // 532

  if (fused) {
    conv_tower<<<GT2, 256, 0, stream>>>(ws, off_in, A, w_cls[0], cls_b + 0,   off_in, C, w_reg[0], reg_b + 0,   off_zp, 1);
    conv_tower<<<GT2, 256, 0, stream>>>(ws, off_A,  B, w_cls[1], cls_b + 256, off_C,  D, w_reg[1], reg_b + 256, off_zp, 1);
    conv_tower<<<GT2, 256, 0, stream>>>(ws, off_B,  A, w_cls[2], cls_b + 512, off_D,  C, w_reg[2], reg_b + 512, off_zp, 1);
    conv_tower<<<GT2, 256, 0, stream>>>(ws, off_A,  B, w_cls[3], cls_b + 768, off_C,  D, w_reg[3], reg_b + 768, off_zp, 1);
    conv_cls_out<<<GC, 256, 0, stream>>>(ws, off_B, out, wco, cls_ob, off_zp);
    conv_reg_out<<<GR, 256, 0, stream>>>(ws, off_D, out, wro, reg_ob, off_zp);
  } else {
    conv_tower<<<GT1, 256, 0, stream>>>(ws, off_in, A, w_cls[0], cls_b + 0,   0, A, w_cls[0], cls_b, off_zp, 0);
    conv_tower<<<GT1, 256, 0, stream>>>(ws, off_A,  B, w_cls[1], cls_b + 256, 0, A, w_cls[0], cls_b, off_zp, 0);
    conv_tower<<<GT1, 256, 0, stream>>>(ws, off_B,  A, w_cls[2], cls_b + 512, 0, A, w_cls[0], cls_b, off_zp, 0);
    conv_tower<<<GT1, 256, 0, stream>>>(ws, off_A,  B, w_cls[3], cls_b + 768, 0, A, w_cls[0], cls_b, off_zp, 0);
    conv_cls_out<<<GC, 256, 0, stream>>>(ws, off_B, out, wco, cls_ob, off_zp);
    conv_tower<<<GT1, 256, 0, stream>>>(ws, off_in, A, w_reg[0], reg_b + 0,   0, A, w_reg[0], reg_b, off_zp, 0);
    conv_tower<<<GT1, 256, 0, stream>>>(ws, off_A,  B, w_reg[1], reg_b + 256, 0, A, w_reg[0], reg_b, off_zp, 0);
    conv_tower<<<GT1, 256, 0, stream>>>(ws, off_B,  A, w_reg[2], reg_b + 512, 0, A, w_reg[0], reg_b, off_zp, 0);
    conv_tower<<<GT1, 256, 0, stream>>>(ws, off_A,  B, w_reg[3], reg_b + 768, 0, A, w_reg[0], reg_b, off_zp, 0);
    conv_reg_out<<<GR, 256, 0, stream>>>(ws, off_B, out, wro, reg_ob, off_zp);
  }
}

// Round 10
// 1012.334 us; speedup vs baseline: 1.0724x; 1.0724x over previous
//
#include <hip/hip_runtime.h>

// RetinaNet head, bf16 implicit-GEMM conv3x3 via MFMA 16x16x32.
// Round 10: exact R8 + bijective XCD-chunked swizzle on cls-out
// (bid = (bid0&7)*321 + (bid0>>3); 2568 = 8*321) so the 6 nt-siblings
// sharing each A-tile land on ONE XCD -> A fetched once per XCD, not 6x.
//  - Towers: R4 core (counted vmcnt(2), 3-deep B, setprio, 96px, 52KB LDS,
//    3 blk/CU, twin-colocating swizzle, dual-branch grid 2272).
//  - cls-out: R2 core (per-tap drain, 2-deep B, 128px, 48KB, no setprio,
//    nt-fastest within chunk), grid 2568 + XCD chunking.
//  - reg-out: R2 core, grid 428.
// Packed B layout per tensor: [nt][cc 8][tap 9][co 128][piece 4][8 bf16],
// piece pre-XOR-swizzled by ((co>>1)&3). A staged linear via global_load_lds,
// read with involutive XOR ((pos>>1)&3)<<4.

typedef __bf16 v8bf __attribute__((ext_vector_type(8)));
typedef float f32x4 __attribute__((ext_vector_type(4)));

__device__ __forceinline__ v8bf zero8() {
  v8bf v;
#pragma unroll
  for (int j = 0; j < 8; ++j) v[j] = (__bf16)0.0f;
  return v;
}

__device__ __forceinline__ void glds16(const void* g, void* l) {
  __builtin_amdgcn_global_load_lds((const __attribute__((address_space(1))) unsigned int*)g,
                                   (__attribute__((address_space(3))) unsigned int*)l, 16, 0, 0);
}

struct Geo { int W, H, HW, pbase, obC, obR, t; };

// 128px tiling: 107 tiles/n (79/20/5/2/1)
__device__ __forceinline__ Geo decode128(int r) {
  Geo g;
  if (r < 79)       { g.W=100;g.H=100;g.HW=10000;g.pbase=0;     g.obC=0;       g.obR=0;      g.t=r; }
  else if (r < 99)  { g.W=50; g.H=50; g.HW=2500; g.pbase=40000; g.obC=7200000; g.obR=360000; g.t=r-79; }
  else if (r < 104) { g.W=25; g.H=25; g.HW=625;  g.pbase=50000; g.obC=9000000; g.obR=450000; g.t=r-99; }
  else if (r < 106) { g.W=13; g.H=13; g.HW=169;  g.pbase=52500; g.obC=9450000; g.obR=472500; g.t=r-104; }
  else              { g.W=7;  g.H=7;  g.HW=49;   g.pbase=53176; g.obC=9571680; g.obR=478584; g.t=r-106; }
  return g;
}
// 96px tiling: 142 tiles/n (105/27/7/2/1)
__device__ __forceinline__ Geo decode96(int r) {
  Geo g;
  if (r < 105)      { g.W=100;g.H=100;g.HW=10000;g.pbase=0;     g.obC=0;       g.obR=0;      g.t=r; }
  else if (r < 132) { g.W=50; g.H=50; g.HW=2500; g.pbase=40000; g.obC=7200000; g.obR=360000; g.t=r-105; }
  else if (r < 139) { g.W=25; g.H=25; g.HW=625;  g.pbase=50000; g.obC=9000000; g.obR=450000; g.t=r-132; }
  else if (r < 141) { g.W=13; g.H=13; g.HW=169;  g.pbase=52500; g.obC=9450000; g.obR=472500; g.t=r-139; }
  else              { g.W=7;  g.H=7;  g.HW=49;   g.pbase=53176; g.obC=9571680; g.obR=478584; g.t=r-141; }
  return g;
}

// ---------------- prep: NCHW fp32 -> NHWC bf16 ----------------
__global__ __launch_bounds__(256)
void prep_in(const float* __restrict__ f0, const float* __restrict__ f1,
             const float* __restrict__ f2, const float* __restrict__ f3,
             const float* __restrict__ f4, __bf16* __restrict__ dst)
{
  int oct = blockIdx.x * 256 + threadIdx.x;
  if (oct >= 1707904) return;             // 13663232/8
  int el = oct << 3;
  int c0 = el & 255;
  int pix = el >> 8;
  const float* s; int HW, hw, n;
  if (pix < 40000)      { s = f0; HW = 10000; int p = pix;         n = p / 10000; hw = p - n * 10000; }
  else if (pix < 50000) { s = f1; HW = 2500;  int p = pix - 40000; n = p / 2500;  hw = p - n * 2500;  }
  else if (pix < 52500) { s = f2; HW = 625;   int p = pix - 50000; n = p / 625;   hw = p - n * 625;   }
  else if (pix < 53176) { s = f3; HW = 169;   int p = pix - 52500; n = p / 169;   hw = p - n * 169;   }
  else                  { s = f4; HW = 49;    int p = pix - 53176; n = p / 49;    hw = p - n * 49;    }
  const float* sp = s + (n * 256 + c0) * HW + hw;
  v8bf v;
#pragma unroll
  for (int j = 0; j < 8; ++j) v[j] = (__bf16)sp[j * HW];
  *(v8bf*)(dst + el) = v;
}

// ------ prep: all 10 weight tensors, OIHW fp32 -> packed B bf16 ------
__global__ __launch_bounds__(256)
void prep_w_all(const float* __restrict__ cls_w, const float* __restrict__ reg_w,
                const float* __restrict__ cls_ow, const float* __restrict__ reg_ow,
                __bf16* __restrict__ wb)
{
  int t = blockIdx.x * 256 + threadIdx.x;
  const float* src; __bf16* dst; int CO, within;
  if (t < 589824) {                        // 8 tower tensors x 73728 octets
    int tensor = t / 73728; within = t % 73728;
    src = tensor < 4 ? cls_w + tensor * 589824 : reg_w + (tensor - 4) * 589824;
    dst = wb + (size_t)tensor * 589824; CO = 256;
  } else if (t < 811008) {                 // cls-out: 6*8*9*128*4
    within = t - 589824; src = cls_ow; dst = wb + 8 * 589824; CO = 720;
  } else {                                 // reg-out: 1*8*9*128*4
    within = t - 811008; src = reg_ow; dst = wb + 8 * 589824 + 1769472; CO = 36;
  }
  int p = within & 3; int xx = within >> 2;
  int co = xx & 127; xx >>= 7;
  int tap = xx % 9; xx /= 9;
  int cc = xx & 7; int nt = xx >> 3;
  int l = p ^ ((co >> 1) & 3);            // logical piece held at physical p
  int cog = nt * 128 + co;
  v8bf v = zero8();
  if (cog < CO) {
    const float* sp = src + ((size_t)cog * 256 + cc * 32 + l * 8) * 9 + tap;
#pragma unroll
    for (int j = 0; j < 8; ++j) v[j] = (__bf16)sp[j * 9];
  }
  *(v8bf*)(dst + ((size_t)(((nt * 8 + cc) * 9 + tap) * 128 + co) * 32 + p * 8)) = v;
}

// ======== TOWER core (R4): 96px x 128co, counted vmcnt, 3-deep B ========
__device__ __forceinline__ void conv_core_t(const char* __restrict__ wsbase,
    unsigned so, unsigned zpoff, const char* __restrict__ wnt,
    int W, int H, int p0, int npx, f32x4 (&acc)[3][4])
{
  __shared__ __align__(16) char ldsA[28672];   // 448 pos * 64B
  __shared__ __align__(16) char ldsB[24576];   // 3 bufs * 8KB (one tap each)
  const int Wp = W + 2;
  const int pend = p0 + npx - 1;
  const int rowlo = p0 / W - 1;
  const int tid = threadIdx.x, lane = tid & 63, wv = tid >> 6;
  const int wn = wv & 1, wm = wv >> 1, la = lane & 15, kg = lane >> 4;

  unsigned offA[7];
#pragma unroll
  for (int j = 0; j < 7; ++j) {
    int pos = (wv * 7 + j) * 16 + (lane >> 2);
    int h = pos / Wp;
    int wc = pos - h * Wp - 1;
    int ar = rowlo + h;
    int pl = (lane & 3) ^ ((pos >> 1) & 3);
    bool ok = (ar >= 0) & (ar < H) & (wc >= 0) & (wc < W);
    offA[j] = ok ? (so + (unsigned)(ar * W + wc) * 512u + (unsigned)pl * 16u)
                 : (zpoff + (unsigned)(lane & 3) * 16u);
  }

  int pos0[3], fvalid[3];
#pragma unroll
  for (int f = 0; f < 3; ++f) {
    int fg = wm * 3 + f;
    fvalid[f] = (fg * 16 < npx);
    int p = p0 + fg * 16 + la; if (p > pend) p = pend;
    int h = p / W;
    pos0[f] = (h - rowlo) * Wp + (p - h * W + 1);
  }

  int boff[4];
#pragma unroll
  for (int nj = 0; nj < 4; ++nj) {
    int co = wn * 64 + nj * 16 + la;
    boff[nj] = (co << 6) + ((kg << 4) ^ (((co >> 1) & 3) << 4));
  }

  const char* bq = wnt + wv * 2048 + lane * 16;
  char* bd = (char*)ldsB + wv * 2048;

#pragma unroll
  for (int j = 0; j < 7; ++j) { glds16(wsbase + offA[j], (char*)ldsA + (wv * 7 + j) * 1024); offA[j] += 64u; }
  glds16(bq, bd); glds16(bq + 1024, bd + 1024);
  glds16(bq + 8192, bd + 8192); glds16(bq + 9216, bd + 9216);

  for (int cc = 0; cc < 8; ++cc) {
#pragma unroll
    for (int tap = 0; tap < 9; ++tap) {
      if (tap == 8) {
        if (cc == 7) { asm volatile("s_waitcnt vmcnt(0)" ::: "memory"); }
        else         { asm volatile("s_waitcnt vmcnt(2)" ::: "memory"); }
      } else         { asm volatile("s_waitcnt vmcnt(2)" ::: "memory"); }
      __builtin_amdgcn_s_barrier();
      if (tap == 0 && cc > 0) {
#pragma unroll
        for (int j = 0; j < 7; ++j) { glds16(wsbase + offA[j], (char*)ldsA + (wv * 7 + j) * 1024); offA[j] += 64u; }
        const char* bs = bq + (cc * 9 + 2) * 8192;
        glds16(bs, bd + 16384); glds16(bs + 1024, bd + 17408);
        asm volatile("s_waitcnt vmcnt(2)" ::: "memory");
        __builtin_amdgcn_s_barrier();
      } else {
        int q = cc * 9 + tap;
        if (q < 70) {
          const char* bs = bq + (q + 2) * 8192;
          char* d = bd + ((tap + 2) % 3) * 8192;
          glds16(bs, d); glds16(bs + 1024, d + 1024);
        }
      }
      const char* bbuf = (const char*)ldsB + (tap % 3) * 8192;
      v8bf bfr[4];
#pragma unroll
      for (int nj = 0; nj < 4; ++nj) bfr[nj] = *(const v8bf*)(bbuf + boff[nj]);
      const int dh = tap / 3 - 1, dw = tap % 3 - 1;
      const int dt = dh * Wp + dw;
      v8bf afr[3];
#pragma unroll
      for (int f = 0; f < 3; ++f)
        if (fvalid[f]) {
          int pos = pos0[f] + dt;
          afr[f] = *(const v8bf*)((const char*)ldsA + ((pos << 6) + ((kg << 4) ^ (((pos >> 1) & 3) << 4))));
        }
      __builtin_amdgcn_s_setprio(1);
#pragma unroll
      for (int f = 0; f < 3; ++f)
        if (fvalid[f])
#pragma unroll
          for (int nj = 0; nj < 4; ++nj)
            acc[f][nj] = __builtin_amdgcn_mfma_f32_16x16x32_bf16(afr[f], bfr[nj], acc[f][nj], 0, 0, 0);
      __builtin_amdgcn_s_setprio(0);
    }
  }
}

// ======== OUT core (R2): 128px x 128co, per-tap drain, 2-deep B ========
__device__ __forceinline__ void conv_core_o(const char* __restrict__ wsbase,
    unsigned so, unsigned zpoff, const char* __restrict__ wnt,
    int W, int H, int p0, int npx, f32x4 (&acc)[4][4])
{
  __shared__ __align__(16) char ldsA[32768];   // 512 pos * 64B
  __shared__ __align__(16) char ldsB[16384];   // 2 bufs * 8KB
  const int Wp = W + 2;
  const int pend = p0 + npx - 1;
  const int rowlo = p0 / W - 1;
  const int tid = threadIdx.x, lane = tid & 63, wv = tid >> 6;
  const int wn = wv & 1, wm = wv >> 1, la = lane & 15, kg = lane >> 4;
  const int i0 = wv * 8;

  unsigned offA[8];
#pragma unroll
  for (int j = 0; j < 8; ++j) {
    int pos = (i0 + j) * 16 + (lane >> 2);
    int h = pos / Wp;
    int wc = pos - h * Wp - 1;
    int ar = rowlo + h;
    int pl = (lane & 3) ^ ((pos >> 1) & 3);
    bool ok = (ar >= 0) & (ar < H) & (wc >= 0) & (wc < W);
    offA[j] = ok ? (so + (unsigned)(ar * W + wc) * 512u + (unsigned)pl * 16u)
                 : (zpoff + (unsigned)(lane & 3) * 16u);
  }

  int pos0[4], fvalid[4];
#pragma unroll
  for (int f = 0; f < 4; ++f) {
    int fg = wm * 4 + f;
    fvalid[f] = (fg * 16 < npx);
    int p = p0 + fg * 16 + la; if (p > pend) p = pend;
    int h = p / W;
    pos0[f] = (h - rowlo) * Wp + (p - h * W + 1);
  }

  int boff[4];
#pragma unroll
  for (int nj = 0; nj < 4; ++nj) {
    int co = wn * 64 + nj * 16 + la;
    boff[nj] = (co << 6) + ((kg << 4) ^ (((co >> 1) & 3) << 4));
  }

  const char* bq = wnt + wv * 2048 + lane * 16;
  char* bd = (char*)ldsB + wv * 2048;

#define ISSUE_AO() do { _Pragma("unroll") \
    for (int j = 0; j < 8; ++j) { glds16(wsbase + offA[j], (char*)ldsA + (i0 + j) * 1024); offA[j] += 64u; } } while (0)
#define ISSUE_BO(q_, buf_) do { const char* s_ = bq + (q_) * 8192; \
    char* d_ = bd + (buf_) * 8192; \
    glds16(s_, d_); glds16(s_ + 1024, d_ + 1024); } while (0)

  ISSUE_AO();
  ISSUE_BO(0, 0);
  int pb = 0;

  for (int cc = 0; cc < 8; ++cc) {
#pragma unroll
    for (int tap = 0; tap < 9; ++tap) {
      __syncthreads();
      int q = cc * 9 + tap;
      if (q < 71) ISSUE_BO(q + 1, pb ^ 1);
      v8bf bfr[4];
#pragma unroll
      for (int nj = 0; nj < 4; ++nj) bfr[nj] = *(const v8bf*)((const char*)ldsB + pb * 8192 + boff[nj]);
      const int dh = tap / 3 - 1, dw = tap % 3 - 1;
      const int dt = dh * Wp + dw;
      v8bf afr[4];
#pragma unroll
      for (int f = 0; f < 4; ++f)
        if (fvalid[f]) {
          int pos = pos0[f] + dt;
          afr[f] = *(const v8bf*)((const char*)ldsA + ((pos << 6) + ((kg << 4) ^ (((pos >> 1) & 3) << 4))));
        }
#pragma unroll
      for (int f = 0; f < 4; ++f)
        if (fvalid[f])
#pragma unroll
          for (int nj = 0; nj < 4; ++nj)
            acc[f][nj] = __builtin_amdgcn_mfma_f32_16x16x32_bf16(afr[f], bfr[nj], acc[f][nj], 0, 0, 0);
      pb ^= 1;
      if (tap == 8 && cc < 7) { __syncthreads(); ISSUE_AO(); }
    }
  }
#undef ISSUE_AO
#undef ISSUE_BO
}

// ---------------- tower conv (96px, R4 kernel), dual-branch ----------------
__global__ __launch_bounds__(256, 2)
void conv_tower(const char* __restrict__ wsbase,
                unsigned so0, __bf16* __restrict__ dst0, const __bf16* __restrict__ w0, const float* __restrict__ b0,
                unsigned so1, __bf16* __restrict__ dst1, const __bf16* __restrict__ w1, const float* __restrict__ b1,
                unsigned zpoff, int half)
{
  int bid = blockIdx.x;
  int br = bid >= half;
  bid -= br ? half : 0;
  unsigned soff = br ? so1 : so0;
  __bf16* dst = br ? dst1 : dst0;
  const __bf16* wt = br ? w1 : w0;
  const float* bias = br ? b1 : b0;

  int x = bid & 7, slot = bid >> 3;        // XCD swizzle: nt twins colocated
  int nt = slot & 1, mtl = slot >> 1;      // mtl 0..70
  int mt = x + (mtl << 3);                 // 0..567
  int n = mt / 142, r = mt - n * 142;
  Geo g = decode96(r);
  int p0 = g.t * 96;
  int npx = g.HW - p0; if (npx > 96) npx = 96;
  unsigned so = soff + (unsigned)(g.pbase + n * g.HW) * 512u;

  f32x4 acc[3][4];
#pragma unroll
  for (int f = 0; f < 3; ++f)
#pragma unroll
    for (int j = 0; j < 4; ++j)
#pragma unroll
      for (int k = 0; k < 4; ++k) acc[f][j][k] = 0.0f;

  conv_core_t(wsbase, so, zpoff, (const char*)(wt + nt * 294912), g.W, g.H, p0, npx, acc);

  int lane = threadIdx.x & 63, wv = threadIdx.x >> 6;
  int wm = wv >> 1, wn = wv & 1, la = lane & 15, kg = lane >> 4;
  size_t pixbase = (size_t)(g.pbase + n * g.HW + p0);
#pragma unroll
  for (int f = 0; f < 3; ++f) {
    int fg = wm * 3 + f;
    if (fg * 16 < npx) {
#pragma unroll
      for (int nj = 0; nj < 4; ++nj) {
        int cob = nt * 128 + wn * 64 + nj * 16 + la;
        float bs = bias[cob];
#pragma unroll
        for (int rr = 0; rr < 4; ++rr) {
          int pl = fg * 16 + kg * 4 + rr;
          if (pl < npx)
            dst[((pixbase + pl) << 8) + cob] = (__bf16)fmaxf(acc[f][nj][rr] + bs, 0.0f);
        }
      }
    }
  }
}

// -------- cls out conv (128px, R2 kernel), grid 2568, XCD-chunked --------
__global__ __launch_bounds__(256, 3)
void conv_cls_out(const char* __restrict__ wsbase, unsigned soA,
                  float* __restrict__ out, const __bf16* __restrict__ wco,
                  const float* __restrict__ bco, unsigned zpoff)
{
  // bijective XCD chunking: 2568 = 8 * 321. XCD x gets work units
  // [x*321, (x+1)*321) in nt-fastest order -> the 6 nt-siblings of each
  // A-tile run on ONE XCD back-to-back (A hot in that XCD's L2).
  int bid0 = blockIdx.x;
  int bid = (bid0 & 7) * 321 + (bid0 >> 3);
  int nt = bid % 6, mt = bid / 6;
  int n = mt / 107, r = mt - n * 107;
  Geo g = decode128(r);
  int p0 = g.t << 7;
  int npx = g.HW - p0; if (npx > 128) npx = 128;
  unsigned so = soA + (unsigned)(g.pbase + n * g.HW) * 512u;

  f32x4 acc[4][4];
#pragma unroll
  for (int f = 0; f < 4; ++f)
#pragma unroll
    for (int j = 0; j < 4; ++j)
#pragma unroll
      for (int k = 0; k < 4; ++k) acc[f][j][k] = 0.0f;

  conv_core_o(wsbase, so, zpoff, (const char*)(wco + nt * 294912), g.W, g.H, p0, npx, acc);

  int lane = threadIdx.x & 63, wv = threadIdx.x >> 6;
  int wm = wv >> 1, wn = wv & 1, la = lane & 15, kg = lane >> 4;
#pragma unroll
  for (int f = 0; f < 4; ++f) {
    int fg = wm * 4 + f;
    if (fg * 16 < npx) {
#pragma unroll
      for (int nj = 0; nj < 4; ++nj) {
        int cob = nt * 128 + wn * 64 + nj * 16 + la;
        if (cob < 720) {
          float bs = bco[cob];
#pragma unroll
          for (int rr = 0; rr < 4; ++rr) {
            int pl = fg * 16 + kg * 4 + rr;
            if (pl < npx) {
              int pix = p0 + pl;
              out[(size_t)n * 9606960 + g.obC + (size_t)pix * 720 + cob] = acc[f][nj][rr] + bs;
            }
          }
        }
      }
    }
  }
}

// ---------------- reg out conv (128px, R2 kernel), grid 428 ----------------
__global__ __launch_bounds__(256, 3)
void conv_reg_out(const char* __restrict__ wsbase, unsigned soA,
                  float* __restrict__ out, const __bf16* __restrict__ wro,
                  const float* __restrict__ bro, unsigned zpoff)
{
  int mt = blockIdx.x;
  int n = mt / 107, r = mt - n * 107;
  Geo g = decode128(r);
  int p0 = g.t << 7;
  int npx = g.HW - p0; if (npx > 128) npx = 128;
  unsigned so = soA + (unsigned)(g.pbase + n * g.HW) * 512u;

  f32x4 acc[4][4];
#pragma unroll
  for (int f = 0; f < 4; ++f)
#pragma unroll
    for (int j = 0; j < 4; ++j)
#pragma unroll
      for (int k = 0; k < 4; ++k) acc[f][j][k] = 0.0f;

  conv_core_o(wsbase, so, zpoff, (const char*)wro, g.W, g.H, p0, npx, acc);

  int lane = threadIdx.x & 63, wv = threadIdx.x >> 6;
  int wm = wv >> 1, wn = wv & 1, la = lane & 15, kg = lane >> 4;
#pragma unroll
  for (int f = 0; f < 4; ++f) {
    int fg = wm * 4 + f;
    if (fg * 16 < npx) {
#pragma unroll
      for (int nj = 0; nj < 4; ++nj) {
        int cob = wn * 64 + nj * 16 + la;
        if (cob < 36) {
#pragma unroll
          for (int rr = 0; rr < 4; ++rr) {
            int pl = fg * 16 + kg * 4 + rr;
            if (pl < npx) {
              int pix = p0 + pl;
              out[38427840 + (size_t)n * 480348 + g.obR + (size_t)pix * 36 + cob] = acc[f][nj][rr] + bro[cob];
            }
          }
        }
      }
    }
  }
}

extern "C" void kernel_launch(void* const* d_in, const int* in_sizes, int n_in,
                              void* d_out, int out_size, void* d_ws, size_t ws_size,
                              hipStream_t stream) {
  (void)in_sizes; (void)n_in; (void)out_size;
  const float* feat0 = (const float*)d_in[0];
  const float* feat1 = (const float*)d_in[1];
  const float* feat2 = (const float*)d_in[2];
  const float* feat3 = (const float*)d_in[3];
  const float* feat4 = (const float*)d_in[4];
  const float* cls_w  = (const float*)d_in[5];
  const float* cls_b  = (const float*)d_in[6];
  const float* cls_ow = (const float*)d_in[7];
  const float* cls_ob = (const float*)d_in[8];
  const float* reg_w  = (const float*)d_in[9];
  const float* reg_b  = (const float*)d_in[10];
  const float* reg_ow = (const float*)d_in[11];
  const float* reg_ob = (const float*)d_in[12];
  float* out = (float*)d_out;

  const size_t ACT = 13663232;             // bf16 elems per activation tensor
  const size_t WSEG = 6782976;             // packed weights total elems
  const char* wsbase = (const char*)d_ws;
  __bf16* base = (__bf16*)d_ws;

  bool fused = ws_size >= (5 * ACT + WSEG + 4096) * 2;
  int nact = fused ? 5 : 3;
  __bf16* A = base + ACT;
  __bf16* B = base + 2 * ACT;
  __bf16* C = fused ? base + 3 * ACT : A;
  __bf16* D = fused ? base + 4 * ACT : B;
  __bf16* wb = base + nact * ACT;

  __bf16* w_cls[4], *w_reg[4];
  for (int li = 0; li < 4; ++li) { w_cls[li] = wb + (size_t)li * 589824; w_reg[li] = wb + (size_t)(4 + li) * 589824; }
  __bf16* wco = wb + 8 * 589824;
  __bf16* wro = wco + 1769472;
  __bf16* zp = wro + 294912;

  unsigned off_in = 0;
  unsigned off_A = (unsigned)(ACT * 2);
  unsigned off_B = (unsigned)(ACT * 4);
  unsigned off_C = fused ? (unsigned)(ACT * 6) : off_A;
  unsigned off_D = fused ? (unsigned)(ACT * 8) : off_B;
  unsigned off_zp = (unsigned)((nact * ACT + WSEG) * 2);

  hipMemsetAsync(zp, 0, 8192, stream);
  prep_in<<<6672, 256, 0, stream>>>(feat0, feat1, feat2, feat3, feat4, base);
  prep_w_all<<<3312, 256, 0, stream>>>(cls_w, reg_w, cls_ow, reg_ow, wb);

  if (fused) {
    conv_tower<<<2272, 256, 0, stream>>>(wsbase, off_in, A, w_cls[0], cls_b + 0,   off_in, C, w_reg[0], reg_b + 0,   off_zp, 1136);
    conv_tower<<<2272, 256, 0, stream>>>(wsbase, off_A,  B, w_cls[1], cls_b + 256, off_C,  D, w_reg[1], reg_b + 256, off_zp, 1136);
    conv_tower<<<2272, 256, 0, stream>>>(wsbase, off_B,  A, w_cls[2], cls_b + 512, off_D,  C, w_reg[2], reg_b + 512, off_zp, 1136);
    conv_tower<<<2272, 256, 0, stream>>>(wsbase, off_A,  B, w_cls[3], cls_b + 768, off_C,  D, w_reg[3], reg_b + 768, off_zp, 1136);
    conv_cls_out<<<2568, 256, 0, stream>>>(wsbase, off_B, out, wco, cls_ob, off_zp);
    conv_reg_out<<<428, 256, 0, stream>>>(wsbase, off_D, out, wro, reg_ob, off_zp);
  } else {
    conv_tower<<<1136, 256, 0, stream>>>(wsbase, off_in, A, w_cls[0], cls_b + 0,   off_in, A, w_cls[0], cls_b, off_zp, 1136);
    conv_tower<<<1136, 256, 0, stream>>>(wsbase, off_A,  B, w_cls[1], cls_b + 256, off_A,  B, w_cls[1], cls_b, off_zp, 1136);
    conv_tower<<<1136, 256, 0, stream>>>(wsbase, off_B,  A, w_cls[2], cls_b + 512, off_B,  A, w_cls[2], cls_b, off_zp, 1136);
    conv_tower<<<1136, 256, 0, stream>>>(wsbase, off_A,  B, w_cls[3], cls_b + 768, off_A,  B, w_cls[3], cls_b, off_zp, 1136);
    conv_cls_out<<<2568, 256, 0, stream>>>(wsbase, off_B, out, wco, cls_ob, off_zp);
    conv_tower<<<1136, 256, 0, stream>>>(wsbase, off_in, A, w_reg[0], reg_b + 0,   off_in, A, w_reg[0], reg_b, off_zp, 1136);
    conv_tower<<<1136, 256, 0, stream>>>(wsbase, off_A,  B, w_reg[1], reg_b + 256, off_A,  B, w_reg[1], reg_b, off_zp, 1136);
    conv_tower<<<1136, 256, 0, stream>>>(wsbase, off_B,  A, w_reg[2], reg_b + 512, off_B,  A, w_reg[2], reg_b, off_zp, 1136);
    conv_tower<<<1136, 256, 0, stream>>>(wsbase, off_A,  B, w_reg[3], reg_b + 768, off_A,  B, w_reg[3], reg_b, off_zp, 1136);
    conv_reg_out<<<428, 256, 0, stream>>>(wsbase, off_B, out, wro, reg_ob, off_zp);
  }
}

// Round 11
// 991.530 us; speedup vs baseline: 1.0949x; 1.0210x over previous
//
#include <hip/hip_runtime.h>

// RetinaNet head, bf16 implicit-GEMM conv3x3 via MFMA 16x16x32.
// Round 11: R10 + (1) coalesced prep_in (cg-major mapping: lanes walk pix ->
// all fp32 reads contiguous; scattered 16B bf16 writes are the cheap side),
// (2) L4 dual-tower halves swapped (reg first, cls second) so cls-out's
// input tensor is written immediately before cls-out launches (R2 adjacency).
//  - Towers: R4 core (counted vmcnt(2), 3-deep B, setprio, 96px, 52KB LDS,
//    twin-colocating swizzle, dual-branch grid 2272).
//  - cls-out: R2 core (per-tap drain, 2-deep B, 128px, 48KB), grid 2568,
//    bijective XCD chunking (bid = (bid0&7)*321 + (bid0>>3)).
//  - reg-out: R2 core, grid 428, launched last.
// Packed B layout per tensor: [nt][cc 8][tap 9][co 128][piece 4][8 bf16],
// piece pre-XOR-swizzled by ((co>>1)&3). A staged linear via global_load_lds,
// read with involutive XOR ((pos>>1)&3)<<4.

typedef __bf16 v8bf __attribute__((ext_vector_type(8)));
typedef float f32x4 __attribute__((ext_vector_type(4)));

__device__ __forceinline__ v8bf zero8() {
  v8bf v;
#pragma unroll
  for (int j = 0; j < 8; ++j) v[j] = (__bf16)0.0f;
  return v;
}

__device__ __forceinline__ void glds16(const void* g, void* l) {
  __builtin_amdgcn_global_load_lds((const __attribute__((address_space(1))) unsigned int*)g,
                                   (__attribute__((address_space(3))) unsigned int*)l, 16, 0, 0);
}

struct Geo { int W, H, HW, pbase, obC, obR, t; };

// 128px tiling: 107 tiles/n (79/20/5/2/1)
__device__ __forceinline__ Geo decode128(int r) {
  Geo g;
  if (r < 79)       { g.W=100;g.H=100;g.HW=10000;g.pbase=0;     g.obC=0;       g.obR=0;      g.t=r; }
  else if (r < 99)  { g.W=50; g.H=50; g.HW=2500; g.pbase=40000; g.obC=7200000; g.obR=360000; g.t=r-79; }
  else if (r < 104) { g.W=25; g.H=25; g.HW=625;  g.pbase=50000; g.obC=9000000; g.obR=450000; g.t=r-99; }
  else if (r < 106) { g.W=13; g.H=13; g.HW=169;  g.pbase=52500; g.obC=9450000; g.obR=472500; g.t=r-104; }
  else              { g.W=7;  g.H=7;  g.HW=49;   g.pbase=53176; g.obC=9571680; g.obR=478584; g.t=r-106; }
  return g;
}
// 96px tiling: 142 tiles/n (105/27/7/2/1)
__device__ __forceinline__ Geo decode96(int r) {
  Geo g;
  if (r < 105)      { g.W=100;g.H=100;g.HW=10000;g.pbase=0;     g.obC=0;       g.obR=0;      g.t=r; }
  else if (r < 132) { g.W=50; g.H=50; g.HW=2500; g.pbase=40000; g.obC=7200000; g.obR=360000; g.t=r-105; }
  else if (r < 139) { g.W=25; g.H=25; g.HW=625;  g.pbase=50000; g.obC=9000000; g.obR=450000; g.t=r-132; }
  else if (r < 141) { g.W=13; g.H=13; g.HW=169;  g.pbase=52500; g.obC=9450000; g.obR=472500; g.t=r-139; }
  else              { g.W=7;  g.H=7;  g.HW=49;   g.pbase=53176; g.obC=9571680; g.obR=478584; g.t=r-141; }
  return g;
}

// ------- prep: NCHW fp32 -> NHWC bf16 (coalesced reads: pix lane-fastest) -------
__global__ __launch_bounds__(256)
void prep_in(const float* __restrict__ f0, const float* __restrict__ f1,
             const float* __restrict__ f2, const float* __restrict__ f3,
             const float* __restrict__ f4, __bf16* __restrict__ dst)
{
  int g = blockIdx.x * 256 + threadIdx.x;
  if (g >= 1712000) return;               // 32 cg * 53500 pix
  int cg = g / 53500;                     // channel octet 0..31
  int pix = g - cg * 53500;
  const float* s; int HW, hw, n;
  if (pix < 40000)      { s = f0; HW = 10000; int p = pix;         n = p / 10000; hw = p - n * 10000; }
  else if (pix < 50000) { s = f1; HW = 2500;  int p = pix - 40000; n = p / 2500;  hw = p - n * 2500;  }
  else if (pix < 52500) { s = f2; HW = 625;   int p = pix - 50000; n = p / 625;   hw = p - n * 625;   }
  else if (pix < 53176) { s = f3; HW = 169;   int p = pix - 52500; n = p / 169;   hw = p - n * 169;   }
  else                  { s = f4; HW = 49;    int p = pix - 53176; n = p / 49;    hw = p - n * 49;    }
  const float* sp = s + (n * 256 + cg * 8) * HW + hw;
  v8bf v;
#pragma unroll
  for (int j = 0; j < 8; ++j) v[j] = (__bf16)sp[j * HW];
  *(v8bf*)(dst + (size_t)pix * 256 + cg * 8) = v;
}

// ------ prep: all 10 weight tensors, OIHW fp32 -> packed B bf16 ------
__global__ __launch_bounds__(256)
void prep_w_all(const float* __restrict__ cls_w, const float* __restrict__ reg_w,
                const float* __restrict__ cls_ow, const float* __restrict__ reg_ow,
                __bf16* __restrict__ wb)
{
  int t = blockIdx.x * 256 + threadIdx.x;
  const float* src; __bf16* dst; int CO, within;
  if (t < 589824) {                        // 8 tower tensors x 73728 octets
    int tensor = t / 73728; within = t % 73728;
    src = tensor < 4 ? cls_w + tensor * 589824 : reg_w + (tensor - 4) * 589824;
    dst = wb + (size_t)tensor * 589824; CO = 256;
  } else if (t < 811008) {                 // cls-out: 6*8*9*128*4
    within = t - 589824; src = cls_ow; dst = wb + 8 * 589824; CO = 720;
  } else {                                 // reg-out: 1*8*9*128*4
    within = t - 811008; src = reg_ow; dst = wb + 8 * 589824 + 1769472; CO = 36;
  }
  int p = within & 3; int xx = within >> 2;
  int co = xx & 127; xx >>= 7;
  int tap = xx % 9; xx /= 9;
  int cc = xx & 7; int nt = xx >> 3;
  int l = p ^ ((co >> 1) & 3);            // logical piece held at physical p
  int cog = nt * 128 + co;
  v8bf v = zero8();
  if (cog < CO) {
    const float* sp = src + ((size_t)cog * 256 + cc * 32 + l * 8) * 9 + tap;
#pragma unroll
    for (int j = 0; j < 8; ++j) v[j] = (__bf16)sp[j * 9];
  }
  *(v8bf*)(dst + ((size_t)(((nt * 8 + cc) * 9 + tap) * 128 + co) * 32 + p * 8)) = v;
}

// ======== TOWER core (R4): 96px x 128co, counted vmcnt, 3-deep B ========
__device__ __forceinline__ void conv_core_t(const char* __restrict__ wsbase,
    unsigned so, unsigned zpoff, const char* __restrict__ wnt,
    int W, int H, int p0, int npx, f32x4 (&acc)[3][4])
{
  __shared__ __align__(16) char ldsA[28672];   // 448 pos * 64B
  __shared__ __align__(16) char ldsB[24576];   // 3 bufs * 8KB (one tap each)
  const int Wp = W + 2;
  const int pend = p0 + npx - 1;
  const int rowlo = p0 / W - 1;
  const int tid = threadIdx.x, lane = tid & 63, wv = tid >> 6;
  const int wn = wv & 1, wm = wv >> 1, la = lane & 15, kg = lane >> 4;

  unsigned offA[7];
#pragma unroll
  for (int j = 0; j < 7; ++j) {
    int pos = (wv * 7 + j) * 16 + (lane >> 2);
    int h = pos / Wp;
    int wc = pos - h * Wp - 1;
    int ar = rowlo + h;
    int pl = (lane & 3) ^ ((pos >> 1) & 3);
    bool ok = (ar >= 0) & (ar < H) & (wc >= 0) & (wc < W);
    offA[j] = ok ? (so + (unsigned)(ar * W + wc) * 512u + (unsigned)pl * 16u)
                 : (zpoff + (unsigned)(lane & 3) * 16u);
  }

  int pos0[3], fvalid[3];
#pragma unroll
  for (int f = 0; f < 3; ++f) {
    int fg = wm * 3 + f;
    fvalid[f] = (fg * 16 < npx);
    int p = p0 + fg * 16 + la; if (p > pend) p = pend;
    int h = p / W;
    pos0[f] = (h - rowlo) * Wp + (p - h * W + 1);
  }

  int boff[4];
#pragma unroll
  for (int nj = 0; nj < 4; ++nj) {
    int co = wn * 64 + nj * 16 + la;
    boff[nj] = (co << 6) + ((kg << 4) ^ (((co >> 1) & 3) << 4));
  }

  const char* bq = wnt + wv * 2048 + lane * 16;
  char* bd = (char*)ldsB + wv * 2048;

#pragma unroll
  for (int j = 0; j < 7; ++j) { glds16(wsbase + offA[j], (char*)ldsA + (wv * 7 + j) * 1024); offA[j] += 64u; }
  glds16(bq, bd); glds16(bq + 1024, bd + 1024);
  glds16(bq + 8192, bd + 8192); glds16(bq + 9216, bd + 9216);

  for (int cc = 0; cc < 8; ++cc) {
#pragma unroll
    for (int tap = 0; tap < 9; ++tap) {
      if (tap == 8) {
        if (cc == 7) { asm volatile("s_waitcnt vmcnt(0)" ::: "memory"); }
        else         { asm volatile("s_waitcnt vmcnt(2)" ::: "memory"); }
      } else         { asm volatile("s_waitcnt vmcnt(2)" ::: "memory"); }
      __builtin_amdgcn_s_barrier();
      if (tap == 0 && cc > 0) {
#pragma unroll
        for (int j = 0; j < 7; ++j) { glds16(wsbase + offA[j], (char*)ldsA + (wv * 7 + j) * 1024); offA[j] += 64u; }
        const char* bs = bq + (cc * 9 + 2) * 8192;
        glds16(bs, bd + 16384); glds16(bs + 1024, bd + 17408);
        asm volatile("s_waitcnt vmcnt(2)" ::: "memory");
        __builtin_amdgcn_s_barrier();
      } else {
        int q = cc * 9 + tap;
        if (q < 70) {
          const char* bs = bq + (q + 2) * 8192;
          char* d = bd + ((tap + 2) % 3) * 8192;
          glds16(bs, d); glds16(bs + 1024, d + 1024);
        }
      }
      const char* bbuf = (const char*)ldsB + (tap % 3) * 8192;
      v8bf bfr[4];
#pragma unroll
      for (int nj = 0; nj < 4; ++nj) bfr[nj] = *(const v8bf*)(bbuf + boff[nj]);
      const int dh = tap / 3 - 1, dw = tap % 3 - 1;
      const int dt = dh * Wp + dw;
      v8bf afr[3];
#pragma unroll
      for (int f = 0; f < 3; ++f)
        if (fvalid[f]) {
          int pos = pos0[f] + dt;
          afr[f] = *(const v8bf*)((const char*)ldsA + ((pos << 6) + ((kg << 4) ^ (((pos >> 1) & 3) << 4))));
        }
      __builtin_amdgcn_s_setprio(1);
#pragma unroll
      for (int f = 0; f < 3; ++f)
        if (fvalid[f])
#pragma unroll
          for (int nj = 0; nj < 4; ++nj)
            acc[f][nj] = __builtin_amdgcn_mfma_f32_16x16x32_bf16(afr[f], bfr[nj], acc[f][nj], 0, 0, 0);
      __builtin_amdgcn_s_setprio(0);
    }
  }
}

// ======== OUT core (R2): 128px x 128co, per-tap drain, 2-deep B ========
__device__ __forceinline__ void conv_core_o(const char* __restrict__ wsbase,
    unsigned so, unsigned zpoff, const char* __restrict__ wnt,
    int W, int H, int p0, int npx, f32x4 (&acc)[4][4])
{
  __shared__ __align__(16) char ldsA[32768];   // 512 pos * 64B
  __shared__ __align__(16) char ldsB[16384];   // 2 bufs * 8KB
  const int Wp = W + 2;
  const int pend = p0 + npx - 1;
  const int rowlo = p0 / W - 1;
  const int tid = threadIdx.x, lane = tid & 63, wv = tid >> 6;
  const int wn = wv & 1, wm = wv >> 1, la = lane & 15, kg = lane >> 4;
  const int i0 = wv * 8;

  unsigned offA[8];
#pragma unroll
  for (int j = 0; j < 8; ++j) {
    int pos = (i0 + j) * 16 + (lane >> 2);
    int h = pos / Wp;
    int wc = pos - h * Wp - 1;
    int ar = rowlo + h;
    int pl = (lane & 3) ^ ((pos >> 1) & 3);
    bool ok = (ar >= 0) & (ar < H) & (wc >= 0) & (wc < W);
    offA[j] = ok ? (so + (unsigned)(ar * W + wc) * 512u + (unsigned)pl * 16u)
                 : (zpoff + (unsigned)(lane & 3) * 16u);
  }

  int pos0[4], fvalid[4];
#pragma unroll
  for (int f = 0; f < 4; ++f) {
    int fg = wm * 4 + f;
    fvalid[f] = (fg * 16 < npx);
    int p = p0 + fg * 16 + la; if (p > pend) p = pend;
    int h = p / W;
    pos0[f] = (h - rowlo) * Wp + (p - h * W + 1);
  }

  int boff[4];
#pragma unroll
  for (int nj = 0; nj < 4; ++nj) {
    int co = wn * 64 + nj * 16 + la;
    boff[nj] = (co << 6) + ((kg << 4) ^ (((co >> 1) & 3) << 4));
  }

  const char* bq = wnt + wv * 2048 + lane * 16;
  char* bd = (char*)ldsB + wv * 2048;

#define ISSUE_AO() do { _Pragma("unroll") \
    for (int j = 0; j < 8; ++j) { glds16(wsbase + offA[j], (char*)ldsA + (i0 + j) * 1024); offA[j] += 64u; } } while (0)
#define ISSUE_BO(q_, buf_) do { const char* s_ = bq + (q_) * 8192; \
    char* d_ = bd + (buf_) * 8192; \
    glds16(s_, d_); glds16(s_ + 1024, d_ + 1024); } while (0)

  ISSUE_AO();
  ISSUE_BO(0, 0);
  int pb = 0;

  for (int cc = 0; cc < 8; ++cc) {
#pragma unroll
    for (int tap = 0; tap < 9; ++tap) {
      __syncthreads();
      int q = cc * 9 + tap;
      if (q < 71) ISSUE_BO(q + 1, pb ^ 1);
      v8bf bfr[4];
#pragma unroll
      for (int nj = 0; nj < 4; ++nj) bfr[nj] = *(const v8bf*)((const char*)ldsB + pb * 8192 + boff[nj]);
      const int dh = tap / 3 - 1, dw = tap % 3 - 1;
      const int dt = dh * Wp + dw;
      v8bf afr[4];
#pragma unroll
      for (int f = 0; f < 4; ++f)
        if (fvalid[f]) {
          int pos = pos0[f] + dt;
          afr[f] = *(const v8bf*)((const char*)ldsA + ((pos << 6) + ((kg << 4) ^ (((pos >> 1) & 3) << 4))));
        }
#pragma unroll
      for (int f = 0; f < 4; ++f)
        if (fvalid[f])
#pragma unroll
          for (int nj = 0; nj < 4; ++nj)
            acc[f][nj] = __builtin_amdgcn_mfma_f32_16x16x32_bf16(afr[f], bfr[nj], acc[f][nj], 0, 0, 0);
      pb ^= 1;
      if (tap == 8 && cc < 7) { __syncthreads(); ISSUE_AO(); }
    }
  }
#undef ISSUE_AO
#undef ISSUE_BO
}

// ---------------- tower conv (96px, R4 kernel), dual-branch ----------------
__global__ __launch_bounds__(256, 2)
void conv_tower(const char* __restrict__ wsbase,
                unsigned so0, __bf16* __restrict__ dst0, const __bf16* __restrict__ w0, const float* __restrict__ b0,
                unsigned so1, __bf16* __restrict__ dst1, const __bf16* __restrict__ w1, const float* __restrict__ b1,
                unsigned zpoff, int half)
{
  int bid = blockIdx.x;
  int br = bid >= half;
  bid -= br ? half : 0;
  unsigned soff = br ? so1 : so0;
  __bf16* dst = br ? dst1 : dst0;
  const __bf16* wt = br ? w1 : w0;
  const float* bias = br ? b1 : b0;

  int x = bid & 7, slot = bid >> 3;        // XCD swizzle: nt twins colocated
  int nt = slot & 1, mtl = slot >> 1;      // mtl 0..70
  int mt = x + (mtl << 3);                 // 0..567
  int n = mt / 142, r = mt - n * 142;
  Geo g = decode96(r);
  int p0 = g.t * 96;
  int npx = g.HW - p0; if (npx > 96) npx = 96;
  unsigned so = soff + (unsigned)(g.pbase + n * g.HW) * 512u;

  f32x4 acc[3][4];
#pragma unroll
  for (int f = 0; f < 3; ++f)
#pragma unroll
    for (int j = 0; j < 4; ++j)
#pragma unroll
      for (int k = 0; k < 4; ++k) acc[f][j][k] = 0.0f;

  conv_core_t(wsbase, so, zpoff, (const char*)(wt + nt * 294912), g.W, g.H, p0, npx, acc);

  int lane = threadIdx.x & 63, wv = threadIdx.x >> 6;
  int wm = wv >> 1, wn = wv & 1, la = lane & 15, kg = lane >> 4;
  size_t pixbase = (size_t)(g.pbase + n * g.HW + p0);
#pragma unroll
  for (int f = 0; f < 3; ++f) {
    int fg = wm * 3 + f;
    if (fg * 16 < npx) {
#pragma unroll
      for (int nj = 0; nj < 4; ++nj) {
        int cob = nt * 128 + wn * 64 + nj * 16 + la;
        float bs = bias[cob];
#pragma unroll
        for (int rr = 0; rr < 4; ++rr) {
          int pl = fg * 16 + kg * 4 + rr;
          if (pl < npx)
            dst[((pixbase + pl) << 8) + cob] = (__bf16)fmaxf(acc[f][nj][rr] + bs, 0.0f);
        }
      }
    }
  }
}

// -------- cls out conv (128px, R2 kernel), grid 2568, XCD-chunked --------
__global__ __launch_bounds__(256, 3)
void conv_cls_out(const char* __restrict__ wsbase, unsigned soA,
                  float* __restrict__ out, const __bf16* __restrict__ wco,
                  const float* __restrict__ bco, unsigned zpoff)
{
  // bijective XCD chunking: 2568 = 8 * 321; the 6 nt-siblings of each
  // A-tile run back-to-back on one XCD (A hot in that XCD's L2).
  int bid0 = blockIdx.x;
  int bid = (bid0 & 7) * 321 + (bid0 >> 3);
  int nt = bid % 6, mt = bid / 6;
  int n = mt / 107, r = mt - n * 107;
  Geo g = decode128(r);
  int p0 = g.t << 7;
  int npx = g.HW - p0; if (npx > 128) npx = 128;
  unsigned so = soA + (unsigned)(g.pbase + n * g.HW) * 512u;

  f32x4 acc[4][4];
#pragma unroll
  for (int f = 0; f < 4; ++f)
#pragma unroll
    for (int j = 0; j < 4; ++j)
#pragma unroll
      for (int k = 0; k < 4; ++k) acc[f][j][k] = 0.0f;

  conv_core_o(wsbase, so, zpoff, (const char*)(wco + nt * 294912), g.W, g.H, p0, npx, acc);

  int lane = threadIdx.x & 63, wv = threadIdx.x >> 6;
  int wm = wv >> 1, wn = wv & 1, la = lane & 15, kg = lane >> 4;
#pragma unroll
  for (int f = 0; f < 4; ++f) {
    int fg = wm * 4 + f;
    if (fg * 16 < npx) {
#pragma unroll
      for (int nj = 0; nj < 4; ++nj) {
        int cob = nt * 128 + wn * 64 + nj * 16 + la;
        if (cob < 720) {
          float bs = bco[cob];
#pragma unroll
          for (int rr = 0; rr < 4; ++rr) {
            int pl = fg * 16 + kg * 4 + rr;
            if (pl < npx) {
              int pix = p0 + pl;
              out[(size_t)n * 9606960 + g.obC + (size_t)pix * 720 + cob] = acc[f][nj][rr] + bs;
            }
          }
        }
      }
    }
  }
}

// ---------------- reg out conv (128px, R2 kernel), grid 428 ----------------
__global__ __launch_bounds__(256, 3)
void conv_reg_out(const char* __restrict__ wsbase, unsigned soA,
                  float* __restrict__ out, const __bf16* __restrict__ wro,
                  const float* __restrict__ bro, unsigned zpoff)
{
  int mt = blockIdx.x;
  int n = mt / 107, r = mt - n * 107;
  Geo g = decode128(r);
  int p0 = g.t << 7;
  int npx = g.HW - p0; if (npx > 128) npx = 128;
  unsigned so = soA + (unsigned)(g.pbase + n * g.HW) * 512u;

  f32x4 acc[4][4];
#pragma unroll
  for (int f = 0; f < 4; ++f)
#pragma unroll
    for (int j = 0; j < 4; ++j)
#pragma unroll
      for (int k = 0; k < 4; ++k) acc[f][j][k] = 0.0f;

  conv_core_o(wsbase, so, zpoff, (const char*)wro, g.W, g.H, p0, npx, acc);

  int lane = threadIdx.x & 63, wv = threadIdx.x >> 6;
  int wm = wv >> 1, wn = wv & 1, la = lane & 15, kg = lane >> 4;
#pragma unroll
  for (int f = 0; f < 4; ++f) {
    int fg = wm * 4 + f;
    if (fg * 16 < npx) {
#pragma unroll
      for (int nj = 0; nj < 4; ++nj) {
        int cob = wn * 64 + nj * 16 + la;
        if (cob < 36) {
#pragma unroll
          for (int rr = 0; rr < 4; ++rr) {
            int pl = fg * 16 + kg * 4 + rr;
            if (pl < npx) {
              int pix = p0 + pl;
              out[38427840 + (size_t)n * 480348 + g.obR + (size_t)pix * 36 + cob] = acc[f][nj][rr] + bro[cob];
            }
          }
        }
      }
    }
  }
}

extern "C" void kernel_launch(void* const* d_in, const int* in_sizes, int n_in,
                              void* d_out, int out_size, void* d_ws, size_t ws_size,
                              hipStream_t stream) {
  (void)in_sizes; (void)n_in; (void)out_size;
  const float* feat0 = (const float*)d_in[0];
  const float* feat1 = (const float*)d_in[1];
  const float* feat2 = (const float*)d_in[2];
  const float* feat3 = (const float*)d_in[3];
  const float* feat4 = (const float*)d_in[4];
  const float* cls_w  = (const float*)d_in[5];
  const float* cls_b  = (const float*)d_in[6];
  const float* cls_ow = (const float*)d_in[7];
  const float* cls_ob = (const float*)d_in[8];
  const float* reg_w  = (const float*)d_in[9];
  const float* reg_b  = (const float*)d_in[10];
  const float* reg_ow = (const float*)d_in[11];
  const float* reg_ob = (const float*)d_in[12];
  float* out = (float*)d_out;

  const size_t ACT = 13663232;             // bf16 elems per activation tensor
  const size_t WSEG = 6782976;             // packed weights total elems
  const char* wsbase = (const char*)d_ws;
  __bf16* base = (__bf16*)d_ws;

  bool fused = ws_size >= (5 * ACT + WSEG + 4096) * 2;
  int nact = fused ? 5 : 3;
  __bf16* A = base + ACT;
  __bf16* B = base + 2 * ACT;
  __bf16* C = fused ? base + 3 * ACT : A;
  __bf16* D = fused ? base + 4 * ACT : B;
  __bf16* wb = base + nact * ACT;

  __bf16* w_cls[4], *w_reg[4];
  for (int li = 0; li < 4; ++li) { w_cls[li] = wb + (size_t)li * 589824; w_reg[li] = wb + (size_t)(4 + li) * 589824; }
  __bf16* wco = wb + 8 * 589824;
  __bf16* wro = wco + 1769472;
  __bf16* zp = wro + 294912;

  unsigned off_in = 0;
  unsigned off_A = (unsigned)(ACT * 2);
  unsigned off_B = (unsigned)(ACT * 4);
  unsigned off_C = fused ? (unsigned)(ACT * 6) : off_A;
  unsigned off_D = fused ? (unsigned)(ACT * 8) : off_B;
  unsigned off_zp = (unsigned)((nact * ACT + WSEG) * 2);

  hipMemsetAsync(zp, 0, 8192, stream);
  prep_in<<<6688, 256, 0, stream>>>(feat0, feat1, feat2, feat3, feat4, base);
  prep_w_all<<<3312, 256, 0, stream>>>(cls_w, reg_w, cls_ow, reg_ow, wb);

  if (fused) {
    conv_tower<<<2272, 256, 0, stream>>>(wsbase, off_in, A, w_cls[0], cls_b + 0,   off_in, C, w_reg[0], reg_b + 0,   off_zp, 1136);
    conv_tower<<<2272, 256, 0, stream>>>(wsbase, off_A,  B, w_cls[1], cls_b + 256, off_C,  D, w_reg[1], reg_b + 256, off_zp, 1136);
    conv_tower<<<2272, 256, 0, stream>>>(wsbase, off_B,  A, w_cls[2], cls_b + 512, off_D,  C, w_reg[2], reg_b + 512, off_zp, 1136);
    // L4: reg half FIRST, cls half SECOND -> cls-out input (B) written last
    conv_tower<<<2272, 256, 0, stream>>>(wsbase, off_C,  D, w_reg[3], reg_b + 768, off_A,  B, w_cls[3], cls_b + 768, off_zp, 1136);
    conv_cls_out<<<2568, 256, 0, stream>>>(wsbase, off_B, out, wco, cls_ob, off_zp);
    conv_reg_out<<<428, 256, 0, stream>>>(wsbase, off_D, out, wro, reg_ob, off_zp);
  } else {
    conv_tower<<<1136, 256, 0, stream>>>(wsbase, off_in, A, w_cls[0], cls_b + 0,   off_in, A, w_cls[0], cls_b, off_zp, 1136);
    conv_tower<<<1136, 256, 0, stream>>>(wsbase, off_A,  B, w_cls[1], cls_b + 256, off_A,  B, w_cls[1], cls_b, off_zp, 1136);
    conv_tower<<<1136, 256, 0, stream>>>(wsbase, off_B,  A, w_cls[2], cls_b + 512, off_B,  A, w_cls[2], cls_b, off_zp, 1136);
    conv_tower<<<1136, 256, 0, stream>>>(wsbase, off_A,  B, w_cls[3], cls_b + 768, off_A,  B, w_cls[3], cls_b, off_zp, 1136);
    conv_cls_out<<<2568, 256, 0, stream>>>(wsbase, off_B, out, wco, cls_ob, off_zp);
    conv_tower<<<1136, 256, 0, stream>>>(wsbase, off_in, A, w_reg[0], reg_b + 0,   off_in, A, w_reg[0], reg_b, off_zp, 1136);
    conv_tower<<<1136, 256, 0, stream>>>(wsbase, off_A,  B, w_reg[1], reg_b + 256, off_A,  B, w_reg[1], reg_b, off_zp, 1136);
    conv_tower<<<1136, 256, 0, stream>>>(wsbase, off_B,  A, w_reg[2], reg_b + 512, off_B,  A, w_reg[2], reg_b, off_zp, 1136);
    conv_tower<<<1136, 256, 0, stream>>>(wsbase, off_A,  B, w_reg[3], reg_b + 768, off_A,  B, w_reg[3], reg_b, off_zp, 1136);
    conv_reg_out<<<428, 256, 0, stream>>>(wsbase, off_B, out, wro, reg_ob, off_zp);
  }
}